// Round 17
// baseline (2059.859 us; speedup 1.0000x reference)
//
#include <hip/hip_runtime.h>

#define Tc 100
#define Hc 512
#define Lc 3
#define H3c 1536
#define HLAY (Hc*Hc)            // elems per layer slice of one hbX ring slot
#define HSLOT (Lc*HLAY)         // elems per hbX ring slot (3-slot ring)
#define HLPAR (6*256*512)       // elems per hbl parity slot

typedef short bf16x8 __attribute__((ext_vector_type(8)));
typedef float f32x4 __attribute__((ext_vector_type(4)));

__device__ __forceinline__ unsigned short f2bf(float f) {
  unsigned int u = __float_as_uint(f);
  u += 0x7FFFu + ((u >> 16) & 1u);   // round-to-nearest-even
  return (unsigned short)(u >> 16);
}

__global__ __launch_bounds__(256) void conv_bf16(const float* __restrict__ src,
                                                 unsigned short* __restrict__ dst,
                                                 int n4) {
  int i = blockIdx.x * 256 + threadIdx.x;
  if (i >= n4) return;
  f32x4 v = *(const f32x4*)(src + (size_t)i * 4);
  ushort4 o;
  o.x = f2bf(v[0]); o.y = f2bf(v[1]); o.z = f2bf(v[2]); o.w = f2bf(v[3]);
  *(ushort4*)(dst + (size_t)i * 4) = o;
}

// Lane-parallel group wait on 32 monotonic per-producer counters (store-
// published, never RMW'd). sc0sc1 polls read the coherence point. Self-drains.
__device__ __forceinline__ void waitg(const int* slots, int tgt, int lane) {
  const int* p = slots + (lane & 31);
  int it = 0;
  for (;;) {
    int v;
    asm volatile("global_load_dword %0, %1, off sc0 sc1\n\ts_waitcnt vmcnt(0)"
                 : "=v"(v) : "v"(p) : "memory");
    if (__all(v >= tgt)) break;
    __builtin_amdgcn_s_sleep(8);
    if (++it > 1000000) break;      // deadlock bug -> fast fail, not hang
  }
}

#define LOADC(dst, ptr) \
  asm volatile("global_load_dwordx4 %0, %1, off sc0 sc1" : "=v"(dst) : "v"(ptr))
#define LOADL(dst, ptr) \
  asm volatile("global_load_dwordx4 %0, %1, off sc0" : "=v"(dst) : "v"(ptr))
#define LOADN(dst, ptr) \
  asm volatile("global_load_dwordx4 %0, %1, off" : "=v"(dst) : "v"(ptr))
#define STORE_H2(ptr, v32) \
  asm volatile("global_store_short %0, %1, off sc0 sc1" :: "v"(ptr), "v"(v32))
#define STORE_HL(ptr, v32) \
  asm volatile("global_store_short %0, %1, off sc0" :: "v"(ptr), "v"(v32))
#define STORE_D(ptr, v32) \
  asm volatile("global_store_dword %0, %1, off sc0 sc1" :: "v"(ptr), "v"(v32))
#define WAITV(n) do { asm volatile("s_waitcnt vmcnt(" #n ")" ::: "memory"); \
                      __builtin_amdgcn_sched_barrier(0); } while (0)
#define MM(a, b, c) c = __builtin_amdgcn_mfma_f32_16x16x32_bf16(a, b, c, 0, 0, 0)

// Persistent dataflow GRU — EXACTLY r15 (1024-thr, 4 waves/SIMD, XCD-local
// hbl, gh-then-gi passes, deferred W1) + ONE delta: hbX ring depth 3
// (slot = t mod 3). W3 (WAR on hbX) relaxes from done[l+1] >= t-1 to
// done[l+1] >= t-2 — two stages of slack, decoupling layer l's period from
// downstream layer l+1's lag. Bisection: r16's NaN bundled 3 deltas; the
// merged-window and memset-removal deltas are parked.
__global__ __launch_bounds__(1024, 4) void gru_persist16(
    const float* __restrict__ x,     // [B,T,A,H] f32 (fallback)
    const short* __restrict__ xb,    // [B,T,A,H] bf16 or nullptr
    const short* __restrict__ wbih,  // [L,3H,H] bf16
    const short* __restrict__ wbhh,  // [L,3H,H] bf16
    const float* __restrict__ bih,   // [L,3H]
    const float* __restrict__ bhh,   // [L,3H]
    short* hb,                       // [3][L][512][512] bf16 ring (sc0sc1)
    short* hbl,                      // [2][6][256][512] bf16 XCD-local (sc0)
    const int* __restrict__ valid,   // [B,T,A] int32
    float* __restrict__ y,           // [B,T,A,H] f32
    int* done) {                     // [6][32] monotonic counters
  __shared__ char wlds[98304];

  const int bid = blockIdx.x;
  const int gi = bid & 7;            // group -> XCD gi
  if (gi >= 6) return;               // 64 dummy blocks (XCDs 6,7 idle)
  const int cb = bid >> 3;           // 0..31
  const int l = gi >> 1;
  const int rb = gi & 1;
  const int c0 = cb * 16;
  const int R0 = rb * 256;

  const int tid = threadIdx.x;
  const int w = tid >> 6;            // wave 0..15
  const int lane = tid & 63;
  const int lrow = lane & 15;
  const int kgrp = lane >> 4;

  const short* wih_l = wbih + (size_t)l * H3c * Hc;
  const short* whh_l = wbhh + (size_t)l * H3c * Hc;

  // ---- one-time LDS weight fill: frag j = m*16+ks, lane-linear ----
#pragma unroll
  for (int it = 0; it < 6; ++it) {
    int j = it * 16 + w;             // 96 fragments, one per wave-iteration
    int m = j >> 4, ks = j & 15;
    int g = (m < 3) ? m : m - 3;
    int n = g * Hc + c0 + lrow;
    const short* src = ((m < 3) ? wih_l : whh_l) + (size_t)n * Hc + ks * 32 + kgrp * 8;
    *(bf16x8*)(wlds + (size_t)j * 1024 + lane * 16) = *(const bf16x8*)src;
  }
  __syncthreads();

  const char* wl = wlds + (lane << 4);

  const float* bihl = bih + l * H3c;
  const float* bhhl = bhh + l * H3c;
  const int c = c0 + lrow;
  const float bi0 = bihl[c], bi1 = bihl[Hc + c], bi2 = bihl[2 * Hc + c];
  const float bh0 = bhhl[c], bh1 = bhhl[Hc + c], bh2 = bhhl[2 * Hc + c];

  f32x4 hreg = f32x4{0.f, 0.f, 0.f, 0.f};   // 4 outputs/thread

  WAITV(0);                          // setup loads drained before counted regions

  for (int t = 0; t < Tc; ++t) {
    // Phase-0 waits: W2 (own t-1), W3 (layer l+1 WAR on hbX, 2-stage slack).
    // W1 deferred to mid-stage (gh-first).
    if (w == 1 && t > 0)           waitg(done + gi * 32, t, lane);
    if (w == 2 && l < 2 && t >= 3) waitg(done + ((l + 1) * 2 + rb) * 32, t - 2, lane);
    __syncthreads();

    const int par = t & 1;           // hbl parity
    const int s3 = t % 3;            // hbX ring slot
    const int rowl = w * 16 + lrow;  // group-local row 0..255

    const short* pHL = hbl + (size_t)(1 - par) * HLPAR + (size_t)gi * 131072
                       + (size_t)rowl * Hc;
    const short* pA = nullptr;
    const float* pXf = x;
    {
      int row = R0 + rowl;           // global row
      if (l > 0) {
        pA = hb + (size_t)s3 * HSLOT + (size_t)(l - 1) * HLAY + (size_t)row * Hc;
      } else {
        int bb = row >> 6, aa = row & 63;
        size_t rofs = ((size_t)bb * Tc + t) * 64 + aa;
        if (xb) pA = xb + rofs * Hc;
        pXf = x + rofs * Hc;
      }
    }

    f32x4 acc[6];
#pragma unroll
    for (int m = 0; m < 6; ++m) acc[m] = f32x4{0.f, 0.f, 0.f, 0.f};

    // rolling window-8 pass: issue 8, consume 4 per WAITV(4) step (literals)
#define ISS4(LOADM, P_, R_, b)                                                     \
      { _Pragma("unroll") for (int q = 0; q < 4; ++q) {                            \
          const int ks = (b) + q;                                                  \
          LOADM(R_[ks & 7], P_ + ks * 32 + (kgrp << 3));                           \
        } }
#define CON4(R_, b, M0)                                                            \
      { _Pragma("unroll") for (int q = 0; q < 4; ++q) {                            \
          const int ks = (b) + q;                                                  \
          bf16x8 B0 = *(const bf16x8*)(wl + (((M0) * 16 + ks) << 10));             \
          bf16x8 B1 = *(const bf16x8*)(wl + ((((M0) + 1) * 16 + ks) << 10));       \
          bf16x8 B2 = *(const bf16x8*)(wl + ((((M0) + 2) * 16 + ks) << 10));       \
          MM(R_[ks & 7], B0, acc[(M0)]);                                           \
          MM(R_[ks & 7], B1, acc[(M0) + 1]);                                       \
          MM(R_[ks & 7], B2, acc[(M0) + 2]);                                       \
        } }
#define PASS(LOADM, P_, M0)                                                        \
      { bf16x8 R_[8];                                                              \
        ISS4(LOADM, P_, R_, 0);  ISS4(LOADM, P_, R_, 4);                           \
        WAITV(4); CON4(R_, 0, M0);                                                 \
        ISS4(LOADM, P_, R_, 8);                                                    \
        WAITV(4); CON4(R_, 4, M0);                                                 \
        ISS4(LOADM, P_, R_, 12);                                                   \
        WAITV(4); CON4(R_, 8, M0);                                                 \
        WAITV(0); CON4(R_, 12, M0);                                                \
      }

    __builtin_amdgcn_sched_barrier(0);
    if (t > 0) {                     // gh pass: XCD-local L2 reads (sc0).
      PASS(LOADL, pHL, 3)            // t=0: h=0 -> gh=bias, pass skipped.
    }
    if (l > 0) {
      if (w == 0) waitg(done + ((l - 1) * 2 + rb) * 32, t + 1, lane);  // W1
      __syncthreads();
      __builtin_amdgcn_sched_barrier(0);
      PASS(LOADC, pA, 0)             // gi once A is published (L3 sc reads)
    } else if (xb) {
      PASS(LOADN, pA, 0)             // x static: no W1, normal cached
    } else {                         // fallback: f32 x via compiler loads
#pragma unroll
      for (int ks = 0; ks < 16; ++ks) {
        const float* _px = pXf + ks * 32 + (kgrp << 3);
        f32x4 v0 = *(const f32x4*)_px;
        f32x4 v1 = *(const f32x4*)(_px + 4);
        bf16x8 t_;
#pragma unroll
        for (int e = 0; e < 4; ++e) {
          t_[e] = (short)f2bf(v0[e]); t_[4 + e] = (short)f2bf(v1[e]);
        }
        bf16x8 B0 = *(const bf16x8*)(wl + ((0 * 16 + ks) << 10));
        bf16x8 B1 = *(const bf16x8*)(wl + ((1 * 16 + ks) << 10));
        bf16x8 B2 = *(const bf16x8*)(wl + ((2 * 16 + ks) << 10));
        MM(t_, B0, acc[0]);
        MM(t_, B1, acc[1]);
        MM(t_, B2, acc[2]);
      }
    }
    __builtin_amdgcn_sched_barrier(0);

    // epilogue: C/D map col=lane&15, row=(lane>>4)*4+reg (m89-verified).
    // Dual store: sc0 -> hbl (own XCD L2), sc0sc1 -> hbX slot s3 (L3).
    short* hout = hb + (size_t)s3 * HSLOT + (size_t)l * HLAY;
    short* houtL = hbl + (size_t)par * HLPAR + (size_t)gi * 131072;
#pragma unroll
    for (int rr = 0; rr < 4; ++rr) {
      int mloc = w * 16 + kgrp * 4 + rr;   // local row 0..255
      int rowg = R0 + mloc;
      int bb = rowg >> 6, aa = rowg & 63;
      size_t vofs = ((size_t)bb * Tc + t) * 64 + aa;
      int vld = valid[vofs];
      float ir = acc[0][rr] + bi0;
      float iz = acc[1][rr] + bi1;
      float in_ = acc[2][rr] + bi2;
      float hr = acc[3][rr] + bh0;
      float hz = acc[4][rr] + bh1;
      float hn = acc[5][rr] + bh2;
      float rg = 1.0f / (1.0f + __expf(-(ir + hr)));
      float zg = 1.0f / (1.0f + __expf(-(iz + hz)));
      float ng = tanhf(in_ + rg * hn);
      float hnew = (1.0f - zg) * ng + zg * hreg[rr];
      if (!vld) hnew = 0.0f;
      hreg[rr] = hnew;
      int hv = (int)f2bf(hnew);
      STORE_HL(houtL + (size_t)mloc * Hc + c, hv);
      if (l < 2) STORE_H2(hout + (size_t)rowg * Hc + c, hv);
      else       y[vofs * Hc + c] = hnew;   // l=2: only y consumer
    }

    asm volatile("s_waitcnt vmcnt(0)" ::: "memory");   // all stores retired
    __syncthreads();                                   // all waves' stores done
    if (tid == 0) {                  // publish: single sc STORE, no RMW
      int v = t + 1;
      STORE_D(done + gi * 32 + cb, v);
    }
    WAITV(0);   // drain publish store: vmcnt clean for next counted region
  }
}

extern "C" void kernel_launch(void* const* d_in, const int* in_sizes, int n_in,
                              void* d_out, int out_size, void* d_ws, size_t ws_size,
                              hipStream_t stream) {
  const float* x = (const float*)d_in[0];
  const int* valid = (const int*)d_in[1];
  const float* w_ih = (const float*)d_in[2];
  const float* w_hh = (const float*)d_in[3];
  const float* b_ih = (const float*)d_in[4];
  const float* b_hh = (const float*)d_in[5];
  float* y = (float*)d_out;

  char* ws = (char*)d_ws;
  const size_t welems = (size_t)Lc * H3c * Hc;            // 2,359,296
  unsigned short* wbih = (unsigned short*)ws;
  unsigned short* wbhh = (unsigned short*)(ws + welems * 2);
  short* hb = (short*)(ws + welems * 4);                  // 4.5 MB 3-slot ring
  const size_t hb_bytes = (size_t)3 * HSLOT * 2;
  int* done = (int*)(ws + welems * 4 + hb_bytes);         // [6][32] = 768 B
  const size_t flags_bytes = 4800;
  const size_t hbl_off = welems * 4 + hb_bytes + flags_bytes;
  const size_t hbl_bytes = (size_t)2 * HLPAR * 2;         // 3.0 MB local ring
  short* hbl = (short*)(ws + hbl_off);
  const size_t xb_off = hbl_off + hbl_bytes;              // 16B aligned
  const size_t xelems = (size_t)8 * Tc * 64 * Hc;         // 26,214,400
  const bool big = ws_size >= xb_off + xelems * 2;
  unsigned short* xbf = big ? (unsigned short*)(ws + xb_off) : nullptr;

  int n4w = (int)(welems / 4);
  conv_bf16<<<(n4w + 255) / 256, 256, 0, stream>>>(w_ih, wbih, n4w);
  conv_bf16<<<(n4w + 255) / 256, 256, 0, stream>>>(w_hh, wbhh, n4w);
  if (big) {
    int n4x = (int)(xelems / 4);
    conv_bf16<<<(n4x + 255) / 256, 256, 0, stream>>>(x, xbf, n4x);
  }
  // zero ring + flags (contiguous), like r15: removes any first-replay
  // garbage doubt; hbl needs no init (first read t=1, W2-gated).
  (void)hipMemsetAsync(hb, 0, hb_bytes + flags_bytes, stream);

  gru_persist16<<<256, 1024, 0, stream>>>(x, (const short*)xbf,
                                          (const short*)wbih, (const short*)wbhh,
                                          b_ih, b_hh, hb, hbl, valid, y, done);
}